// Round 1
// baseline (987.106 us; speedup 1.0000x reference)
//
#include <hip/hip_runtime.h>
#include <math.h>

#define BATCH 16
#define CIN   256
#define NPIX  4096   // 64*64
#define NP4   1024   // 32*32
#define DQK   32     // C/8
#define DV    128    // C/2
#define QT    64     // query tile
#define KT    32     // key tile

// ---------------- phi conv + 2x2 maxpool -> K [B][32][1024] ----------------
__global__ __launch_bounds__(256) void conv_phi_pool_k(
    const float* __restrict__ x, const float* __restrict__ w,
    const float* __restrict__ bias, float* __restrict__ Kout)
{
    const int b   = blockIdx.y;
    const int pix = threadIdx.x & 63;
    const int og  = __builtin_amdgcn_readfirstlane(threadIdx.x >> 6); // 0..3, wave-uniform
    const int p   = blockIdx.x * 64 + pix;            // pooled pixel 0..1023
    const int h2 = p >> 5, w2 = p & 31;
    const int n00 = (h2 << 7) + (w2 << 1);            // 2*h2*64 + 2*w2
    const float* xb = x + (size_t)b * CIN * NPIX + n00;

    float a0[8], a1[8], a2[8], a3[8];
#pragma unroll
    for (int i = 0; i < 8; ++i) {
        float bv = bias[og * 8 + i];
        a0[i] = bv; a1[i] = bv; a2[i] = bv; a3[i] = bv;
    }
    for (int c = 0; c < CIN; ++c) {
        const float* xc = xb + (size_t)c * NPIX;
        float x0 = xc[0], x1 = xc[1], x2 = xc[64], x3 = xc[65];
#pragma unroll
        for (int i = 0; i < 8; ++i) {
            float wv = w[(og * 8 + i) * CIN + c];
            a0[i] = fmaf(wv, x0, a0[i]);
            a1[i] = fmaf(wv, x1, a1[i]);
            a2[i] = fmaf(wv, x2, a2[i]);
            a3[i] = fmaf(wv, x3, a3[i]);
        }
    }
    float* kb = Kout + (size_t)b * DQK * NP4 + p;
#pragma unroll
    for (int i = 0; i < 8; ++i)
        kb[(size_t)(og * 8 + i) * NP4] = fmaxf(fmaxf(a0[i], a1[i]), fmaxf(a2[i], a3[i]));
}

// ---------------- g conv + 2x2 maxpool -> V [B][128][1024] ----------------
__global__ __launch_bounds__(256) void conv_g_pool_k(
    const float* __restrict__ x, const float* __restrict__ w,
    const float* __restrict__ bias, float* __restrict__ Vout)
{
    const int b   = blockIdx.y;
    const int pix = threadIdx.x & 31;
    const int og  = threadIdx.x >> 5;                 // 0..7 (not wave-uniform)
    const int p   = blockIdx.x * 32 + pix;
    const int h2 = p >> 5, w2 = p & 31;
    const int n00 = (h2 << 7) + (w2 << 1);
    const float* xb = x + (size_t)b * CIN * NPIX + n00;

    float a0[16], a1[16], a2[16], a3[16];
#pragma unroll
    for (int i = 0; i < 16; ++i) {
        float bv = bias[og * 16 + i];
        a0[i] = bv; a1[i] = bv; a2[i] = bv; a3[i] = bv;
    }
    for (int c = 0; c < CIN; ++c) {
        const float* xc = xb + (size_t)c * NPIX;
        float x0 = xc[0], x1 = xc[1], x2 = xc[64], x3 = xc[65];
#pragma unroll
        for (int i = 0; i < 16; ++i) {
            float wv = w[(og * 16 + i) * CIN + c];
            a0[i] = fmaf(wv, x0, a0[i]);
            a1[i] = fmaf(wv, x1, a1[i]);
            a2[i] = fmaf(wv, x2, a2[i]);
            a3[i] = fmaf(wv, x3, a3[i]);
        }
    }
    float* vb = Vout + (size_t)b * DV * NP4 + p;
#pragma unroll
    for (int i = 0; i < 16; ++i)
        vb[(size_t)(og * 16 + i) * NP4] = fmaxf(fmaxf(a0[i], a1[i]), fmaxf(a2[i], a3[i]));
}

// ------- fused: theta conv + flash attention + final conv + residual -------
__global__ __launch_bounds__(256) void attn_fused_k(
    const float* __restrict__ x, const float* __restrict__ w_theta,
    const float* __restrict__ b_theta, const float* __restrict__ Kin,
    const float* __restrict__ Vin, const float* __restrict__ w_attn,
    const float* __restrict__ b_attn, const float* __restrict__ sigma,
    float* __restrict__ out)
{
    __shared__ __align__(16) union {
        float qs[QT][36];                              // 9216 B (phase 0)
        struct {
            float ks[KT][36];                          // 4608 B  k-major, rows 16B-aligned
            float vs[KT][132];                         // 16896 B k-major, rows 16B-aligned
            float ps[QT][33];                          // 8448 B
        } lp;                                          // (phase 1: flash loop)
        float pred[4][32][65];                         // 33280 B (phase 2: epilogue)
    } u;
    __shared__ float scl_s[QT], m_s[QT], l_s[QT];

    const int b  = blockIdx.y;
    const int q0 = blockIdx.x * QT;
    const int t  = threadIdx.x;
    const int qi = t & 63;                              // owned query row
    const int cg = __builtin_amdgcn_readfirstlane(t >> 6); // 0..3, wave-uniform

    // ---- phase 0: fused theta conv. Thread (qi,cg) computes 8 of 32 Q dims.
    {
        const float* xb = x + (size_t)b * CIN * NPIX + q0 + qi;
        float qa[8];
#pragma unroll
        for (int i = 0; i < 8; ++i) qa[i] = b_theta[cg * 8 + i];
        for (int c = 0; c < CIN; ++c) {
            float xv = xb[(size_t)c * NPIX];
#pragma unroll
            for (int i = 0; i < 8; ++i)
                qa[i] = fmaf(w_theta[(cg * 8 + i) * CIN + c], xv, qa[i]);
        }
#pragma unroll
        for (int i = 0; i < 8; ++i) u.qs[qi][cg * 8 + i] = qa[i];
    }
    if (t < QT) { m_s[t] = -1e30f; l_s[t] = 0.f; }
    __syncthreads();

    float qreg[DQK];
#pragma unroll
    for (int o = 0; o < DQK; ++o) qreg[o] = u.qs[qi][o];
    float acc[32];                                      // O channels cg*32..cg*32+31
#pragma unroll
    for (int i = 0; i < 32; ++i) acc[i] = 0.f;
    __syncthreads();                                    // qs dead; loop may reuse union

    const float* Kb = Kin + (size_t)b * DQK * NP4;
    const float* Vb = Vin + (size_t)b * DV * NP4;

    // ---- phase 1: flash loop over 32 key tiles of 32
    for (int k0 = 0; k0 < NP4; k0 += KT) {
        // stage K tile (transposed to k-major) and V tile (k-major)
        for (int idx = t; idx < DQK * KT; idx += 256) {
            int c = idx >> 5, k = idx & 31;
            u.lp.ks[k][c] = Kb[(size_t)c * NP4 + k0 + k];
        }
        for (int idx = t; idx < DV * KT; idx += 256) {
            int c = idx >> 5, k = idx & 31;
            u.lp.vs[k][c] = Vb[(size_t)c * NP4 + k0 + k];
        }
        __syncthreads();

        // S block: thread (qi,cg) computes keys cg*8..cg*8+7 for its query
#pragma unroll
        for (int kk = 0; kk < 8; ++kk) {
            int k = cg * 8 + kk;
            const float4* kr = reinterpret_cast<const float4*>(&u.lp.ks[k][0]);
            float s = 0.f;
#pragma unroll
            for (int c4 = 0; c4 < 8; ++c4) {
                float4 kv = kr[c4];
                s = fmaf(qreg[c4 * 4 + 0], kv.x, s);
                s = fmaf(qreg[c4 * 4 + 1], kv.y, s);
                s = fmaf(qreg[c4 * 4 + 2], kv.z, s);
                s = fmaf(qreg[c4 * 4 + 3], kv.w, s);
            }
            u.lp.ps[qi][k] = s;
        }
        __syncthreads();

        // online softmax (wave 0 only)
        if (cg == 0) {
            float m_old = m_s[qi];
            float mx = m_old;
#pragma unroll
            for (int k = 0; k < KT; ++k) mx = fmaxf(mx, u.lp.ps[qi][k]);
            float sum = 0.f;
#pragma unroll
            for (int k = 0; k < KT; ++k) {
                float pv = __expf(u.lp.ps[qi][k] - mx);
                u.lp.ps[qi][k] = pv;
                sum += pv;
            }
            float sc = __expf(m_old - mx);
            scl_s[qi] = sc;
            m_s[qi]  = mx;
            l_s[qi]  = l_s[qi] * sc + sum;
        }
        __syncthreads();

        // accumulate O += P * V  (thread owns 32 V-channels)
        float sc = scl_s[qi];
#pragma unroll
        for (int i = 0; i < 32; ++i) acc[i] *= sc;
#pragma unroll
        for (int kk = 0; kk < KT; ++kk) {
            float pv = u.lp.ps[qi][kk];
            const float4* vr = reinterpret_cast<const float4*>(&u.lp.vs[kk][cg * 32]);
#pragma unroll
            for (int i4 = 0; i4 < 8; ++i4) {
                float4 vv = vr[i4];
                acc[i4 * 4 + 0] = fmaf(pv, vv.x, acc[i4 * 4 + 0]);
                acc[i4 * 4 + 1] = fmaf(pv, vv.y, acc[i4 * 4 + 1]);
                acc[i4 * 4 + 2] = fmaf(pv, vv.z, acc[i4 * 4 + 2]);
                acc[i4 * 4 + 3] = fmaf(pv, vv.w, acc[i4 * 4 + 3]);
            }
        }
        __syncthreads();
    }

    // normalize
    float rinv = 1.0f / l_s[qi];
#pragma unroll
    for (int i = 0; i < 32; ++i) acc[i] *= rinv;

    // ---- phase 2: fused final conv (256x128) + residual, chunked over o
    const float sg = sigma[0];
    const int ob = t >> 6;   // == cg, used for reduce role
    for (int och = 0; och < 8; ++och) {
#pragma unroll
        for (int oo = 0; oo < 32; ++oo) {
            int o = och * 32 + oo;
            float s = 0.f;
#pragma unroll
            for (int i = 0; i < 32; ++i)
                s = fmaf(w_attn[o * DV + cg * 32 + i], acc[i], s);
            u.pred[cg][oo][qi] = s;
        }
        __syncthreads();
#pragma unroll
        for (int j = 0; j < 8; ++j) {
            int oo = ob * 8 + j;
            int o  = och * 32 + oo;
            float y = b_attn[o] + u.pred[0][oo][qi] + u.pred[1][oo][qi]
                    + u.pred[2][oo][qi] + u.pred[3][oo][qi];
            size_t idx = ((size_t)b * 256 + o) * NPIX + q0 + qi;
            out[idx] = fmaf(sg, y, x[idx]);
        }
        __syncthreads();
    }
}

extern "C" void kernel_launch(void* const* d_in, const int* in_sizes, int n_in,
                              void* d_out, int out_size, void* d_ws, size_t ws_size,
                              hipStream_t stream) {
    const float* x       = (const float*)d_in[0];
    const float* w_theta = (const float*)d_in[1];
    const float* b_theta = (const float*)d_in[2];
    const float* w_phi   = (const float*)d_in[3];
    const float* b_phi   = (const float*)d_in[4];
    const float* w_g     = (const float*)d_in[5];
    const float* b_g     = (const float*)d_in[6];
    const float* w_attn  = (const float*)d_in[7];
    const float* b_attn  = (const float*)d_in[8];
    const float* sigma   = (const float*)d_in[9];
    float* out  = (float*)d_out;
    float* Kbuf = (float*)d_ws;                         // 16*32*1024 floats
    float* Vbuf = Kbuf + (size_t)BATCH * DQK * NP4;     // 16*128*1024 floats

    conv_phi_pool_k<<<dim3(NP4 / 64, BATCH), 256, 0, stream>>>(x, w_phi, b_phi, Kbuf);
    conv_g_pool_k <<<dim3(NP4 / 32, BATCH), 256, 0, stream>>>(x, w_g, b_g, Vbuf);
    attn_fused_k  <<<dim3(NPIX / QT, BATCH), 256, 0, stream>>>(
        x, w_theta, b_theta, Kbuf, Vbuf, w_attn, b_attn, sigma, out);
}

// Round 2
// 253.148 us; speedup vs baseline: 3.8993x; 3.8993x over previous
//
#include <hip/hip_runtime.h>
#include <math.h>

#define BATCH 16
#define CIN   256
#define NPIX  4096   // 64*64
#define NP4   1024   // 32*32 pooled
#define DQK   32     // C/8
#define DV    128    // C/2
#define KT    64     // keys per flash tile
#define QW    32     // queries per wave
#define QT    128    // queries per WG (4 waves)

typedef __attribute__((ext_vector_type(8)))  short short8v;
typedef __attribute__((ext_vector_type(16))) float f32x16;

#define ZERO16 {0.f,0.f,0.f,0.f,0.f,0.f,0.f,0.f,0.f,0.f,0.f,0.f,0.f,0.f,0.f,0.f}

__device__ __forceinline__ unsigned short f2bf(float f) {
    unsigned u = __float_as_uint(f);
    u += 0x7FFFu + ((u >> 16) & 1u);          // round-to-nearest-even
    return (unsigned short)(u >> 16);
}

__device__ __forceinline__ void gload_lds16(const void* g, void* l) {
    __builtin_amdgcn_global_load_lds(
        (const __attribute__((address_space(1))) unsigned int*)g,
        (__attribute__((address_space(3))) unsigned int*)l, 16, 0, 0);
}

// ---------------- theta conv -> Qg[b][p][d] bf16 (A/B-frag row-major) -------
__global__ __launch_bounds__(256) void conv_theta_k(
    const float* __restrict__ x, const float* __restrict__ w,
    const float* __restrict__ bias, unsigned short* __restrict__ Qg)
{
    const int b  = blockIdx.y;
    const int p  = blockIdx.x * 64 + (threadIdx.x & 63);
    const int og = __builtin_amdgcn_readfirstlane(threadIdx.x >> 6); // 0..3
    const float* xb = x + (size_t)b * CIN * NPIX + p;
    float a[8];
#pragma unroll
    for (int i = 0; i < 8; ++i) a[i] = bias[og * 8 + i];
    for (int c = 0; c < CIN; ++c) {
        float xv = xb[(size_t)c * NPIX];
#pragma unroll
        for (int i = 0; i < 8; ++i)
            a[i] = fmaf(w[(og * 8 + i) * CIN + c], xv, a[i]);
    }
    unsigned short tmp[8];
#pragma unroll
    for (int i = 0; i < 8; ++i) tmp[i] = f2bf(a[i]);
    *(short8v*)&Qg[((size_t)b * NPIX + p) * DQK + og * 8] = *(short8v*)tmp;
}

// ------- phi conv + 2x2 maxpool -> Kg[b][d>>3][p][d&7] bf16 ----------------
__global__ __launch_bounds__(256) void conv_phi_pool_k(
    const float* __restrict__ x, const float* __restrict__ w,
    const float* __restrict__ bias, unsigned short* __restrict__ Kg)
{
    const int b   = blockIdx.y;
    const int pix = threadIdx.x & 63;
    const int og  = __builtin_amdgcn_readfirstlane(threadIdx.x >> 6); // 0..3
    const int p   = blockIdx.x * 64 + pix;              // pooled pixel
    const int h2 = p >> 5, w2 = p & 31;
    const int n00 = (h2 << 7) + (w2 << 1);
    const float* xb = x + (size_t)b * CIN * NPIX + n00;

    float a0[8], a1[8], a2[8], a3[8];
#pragma unroll
    for (int i = 0; i < 8; ++i) {
        float bv = bias[og * 8 + i];
        a0[i] = bv; a1[i] = bv; a2[i] = bv; a3[i] = bv;
    }
    for (int c = 0; c < CIN; ++c) {
        const float* xc = xb + (size_t)c * NPIX;
        float x0 = xc[0], x1 = xc[1], x2 = xc[64], x3 = xc[65];
#pragma unroll
        for (int i = 0; i < 8; ++i) {
            float wv = w[(og * 8 + i) * CIN + c];
            a0[i] = fmaf(wv, x0, a0[i]);
            a1[i] = fmaf(wv, x1, a1[i]);
            a2[i] = fmaf(wv, x2, a2[i]);
            a3[i] = fmaf(wv, x3, a3[i]);
        }
    }
    unsigned short tmp[8];
#pragma unroll
    for (int i = 0; i < 8; ++i)
        tmp[i] = f2bf(fmaxf(fmaxf(a0[i], a1[i]), fmaxf(a2[i], a3[i])));
    *(short8v*)&Kg[(((size_t)b * 4 + og) * NP4 + p) * 8] = *(short8v*)tmp;
}

// ------- g conv + 2x2 maxpool -> Vg[b][p>>3][c][p&7] bf16 ------------------
__global__ __launch_bounds__(256) void conv_g_pool_k(
    const float* __restrict__ x, const float* __restrict__ w,
    const float* __restrict__ bias, unsigned short* __restrict__ Vg)
{
    const int b   = blockIdx.y;
    const int pix = threadIdx.x & 31;
    const int og  = threadIdx.x >> 5;                   // 0..7
    const int p   = blockIdx.x * 32 + pix;
    const int h2 = p >> 5, w2 = p & 31;
    const int n00 = (h2 << 7) + (w2 << 1);
    const float* xb = x + (size_t)b * CIN * NPIX + n00;

    float a0[16], a1[16], a2[16], a3[16];
#pragma unroll
    for (int i = 0; i < 16; ++i) {
        float bv = bias[og * 16 + i];
        a0[i] = bv; a1[i] = bv; a2[i] = bv; a3[i] = bv;
    }
    for (int c = 0; c < CIN; ++c) {
        const float* xc = xb + (size_t)c * NPIX;
        float x0 = xc[0], x1 = xc[1], x2 = xc[64], x3 = xc[65];
#pragma unroll
        for (int i = 0; i < 16; ++i) {
            float wv = w[(og * 16 + i) * CIN + c];
            a0[i] = fmaf(wv, x0, a0[i]);
            a1[i] = fmaf(wv, x1, a1[i]);
            a2[i] = fmaf(wv, x2, a2[i]);
            a3[i] = fmaf(wv, x3, a3[i]);
        }
    }
    unsigned short* vb = Vg + ((size_t)b * 128 + (p >> 3)) * DV * 8 + (p & 7);
#pragma unroll
    for (int i = 0; i < 16; ++i) {
        int c = og * 16 + i;
        vb[(size_t)c * 8] = f2bf(fmaxf(fmaxf(a0[i], a1[i]), fmaxf(a2[i], a3[i])));
    }
}

// ---------------- w_attn fp32 -> bf16 ---------------------------------------
__global__ void wcvt_k(const float* __restrict__ w, unsigned short* __restrict__ o, int n)
{
    int i = blockIdx.x * 256 + threadIdx.x;
    if (i < n) o[i] = f2bf(w[i]);
}

// ------- fused: flash attention (MFMA) + final conv (MFMA) + residual -------
__global__ __launch_bounds__(256, 2) void flash_k(
    const unsigned short* __restrict__ Qg, const unsigned short* __restrict__ Kg,
    const unsigned short* __restrict__ Vg, const unsigned short* __restrict__ wab,
    const float* __restrict__ b_attn, const float* __restrict__ sigma,
    const float* __restrict__ x, float* __restrict__ out)
{
    __shared__ __align__(16) union {
        struct {
            unsigned short ks[4 * KT * 8];   // [d>>3][k 64][d&7]  4KB
            unsigned short vs[8 * DV * 8];   // [k>>3][c 128][k&7] 16KB
        } s;
        unsigned short os[4][16 * QW * 8];   // per-wave [c>>3][q 32][c&7] 32KB
    } u;

    const int b   = blockIdx.y;
    const int t   = threadIdx.x;
    const int wv  = t >> 6;
    const int l   = t & 63;
    const int h   = l >> 5;
    const int q31 = l & 31;
    const int p0  = blockIdx.x * QT + wv * QW;          // wave's pixel base

    // Q B-fragments: lane holds q=p0+q31, d = ds*16 + h*8 + e
    short8v qf0 = *(const short8v*)&Qg[((size_t)b * NPIX + p0 + q31) * DQK + h * 8];
    short8v qf1 = *(const short8v*)&Qg[((size_t)b * NPIX + p0 + q31) * DQK + 16 + h * 8];

    f32x16 o0 = ZERO16, o1 = ZERO16, o2 = ZERO16, o3 = ZERO16;
    float m = -3.0e38f, lsum = 0.f;

    const size_t kbase = (size_t)b * 4 * NP4 * 8;       // ushort index
    const size_t vbase = (size_t)b * 128 * DV * 8;

    for (int kt = 0; kt < NP4 / KT; ++kt) {
        // ---- stage K (4x1KB) + V (16x1KB), 5 chunks per wave
#pragma unroll
        for (int j = 0; j < 5; ++j) {
            int cid = wv * 5 + j;
            if (cid < 4) {
                gload_lds16(&Kg[kbase + ((size_t)cid * NP4 + kt * KT + l) * 8],
                            &u.s.ks[cid * 512]);
            } else {
                int c2 = cid - 4;
                gload_lds16(&Vg[vbase + (size_t)kt * 8192 + c2 * 512 + l * 8],
                            &u.s.vs[c2 * 512]);
            }
        }
        __syncthreads();

        // ---- S^T = K * Q^T : D[k][q], lane: q=l&31, k = kb*32 + (r&3)+8*(r>>2)+4h
        f32x16 s0 = ZERO16, s1 = ZERO16;
        {
            short8v kf;
            kf = *(const short8v*)&u.s.ks[((0 + h) * KT + 0 + q31) * 8];
            s0 = __builtin_amdgcn_mfma_f32_32x32x16_bf16(kf, qf0, s0, 0, 0, 0);
            kf = *(const short8v*)&u.s.ks[((2 + h) * KT + 0 + q31) * 8];
            s0 = __builtin_amdgcn_mfma_f32_32x32x16_bf16(kf, qf1, s0, 0, 0, 0);
            kf = *(const short8v*)&u.s.ks[((0 + h) * KT + 32 + q31) * 8];
            s1 = __builtin_amdgcn_mfma_f32_32x32x16_bf16(kf, qf0, s1, 0, 0, 0);
            kf = *(const short8v*)&u.s.ks[((2 + h) * KT + 32 + q31) * 8];
            s1 = __builtin_amdgcn_mfma_f32_32x32x16_bf16(kf, qf1, s1, 0, 0, 0);
        }

        // ---- online softmax: lane owns one q (=l&31), 32 of 64 keys
        float mx = s0[0];
#pragma unroll
        for (int r = 1; r < 16; ++r) mx = fmaxf(mx, s0[r]);
#pragma unroll
        for (int r = 0; r < 16; ++r) mx = fmaxf(mx, s1[r]);
        mx = fmaxf(mx, __shfl_xor(mx, 32));

        bool nskip = !__all(mx <= m + 8.0f);            // defer-max (T13)
        if (nskip) {
            float mnew = fmaxf(m, mx);
            float scale = __expf(m - mnew);
            m = mnew;
            lsum *= scale;
#pragma unroll
            for (int r = 0; r < 16; ++r) {
                float sc = __shfl(scale, (r & 3) + 8 * (r >> 2) + 4 * h);
                o0[r] *= sc; o1[r] *= sc; o2[r] *= sc; o3[r] *= sc;
            }
        }

        float rs = 0.f;
#pragma unroll
        for (int r = 0; r < 16; ++r) { s0[r] = __expf(s0[r] - m); rs += s0[r]; }
#pragma unroll
        for (int r = 0; r < 16; ++r) { s1[r] = __expf(s1[r] - m); rs += s1[r]; }
        rs += __shfl_xor(rs, 32);
        lsum += rs;

        // ---- P -> bf16 PV A-fragments (cvt_pk + partner swap, T12)
        unsigned ca[8], cb[8], da[8], db[8];
#pragma unroll
        for (int j = 0; j < 8; ++j) {
            asm("v_cvt_pk_bf16_f32 %0, %1, %2" : "=v"(ca[j]) : "v"(s0[2*j]), "v"(s0[2*j+1]));
            asm("v_cvt_pk_bf16_f32 %0, %1, %2" : "=v"(cb[j]) : "v"(s1[2*j]), "v"(s1[2*j+1]));
        }
#pragma unroll
        for (int j = 0; j < 8; ++j) {
            da[j] = (unsigned)__shfl_xor((int)ca[j], 32);
            db[j] = (unsigned)__shfl_xor((int)cb[j], 32);
        }
        union { unsigned uu[4]; short8v v; } pa[4];
#pragma unroll
        for (int ksl = 0; ksl < 2; ++ksl) {
            pa[ksl].uu[0]     = h ? da[4*ksl+2] : ca[4*ksl+0];
            pa[ksl].uu[1]     = h ? da[4*ksl+3] : ca[4*ksl+1];
            pa[ksl].uu[2]     = h ? ca[4*ksl+2] : da[4*ksl+0];
            pa[ksl].uu[3]     = h ? ca[4*ksl+3] : da[4*ksl+1];
            pa[2+ksl].uu[0]   = h ? db[4*ksl+2] : cb[4*ksl+0];
            pa[2+ksl].uu[1]   = h ? db[4*ksl+3] : cb[4*ksl+1];
            pa[2+ksl].uu[2]   = h ? cb[4*ksl+2] : db[4*ksl+0];
            pa[2+ksl].uu[3]   = h ? cb[4*ksl+3] : db[4*ksl+1];
        }

        // ---- O += P * V : 16 MFMAs, B-frags linear in LDS
#pragma unroll
        for (int ks16 = 0; ks16 < 4; ++ks16) {
            const unsigned short* vrow = &u.s.vs[((ks16 * 2 + h) * DV) * 8];
            o0 = __builtin_amdgcn_mfma_f32_32x32x16_bf16(pa[ks16].v,
                     *(const short8v*)&vrow[(0  + q31) * 8], o0, 0, 0, 0);
            o1 = __builtin_amdgcn_mfma_f32_32x32x16_bf16(pa[ks16].v,
                     *(const short8v*)&vrow[(32 + q31) * 8], o1, 0, 0, 0);
            o2 = __builtin_amdgcn_mfma_f32_32x32x16_bf16(pa[ks16].v,
                     *(const short8v*)&vrow[(64 + q31) * 8], o2, 0, 0, 0);
            o3 = __builtin_amdgcn_mfma_f32_32x32x16_bf16(pa[ks16].v,
                     *(const short8v*)&vrow[(96 + q31) * 8], o3, 0, 0, 0);
        }
        __syncthreads();
    }

    // ---- normalize, write O to per-wave LDS as bf16 [c>>3][q][c&7]
    float rinv = 1.0f / lsum;
    unsigned short* osw = u.os[wv];
#pragma unroll
    for (int r = 0; r < 16; ++r) {
        float rn = __shfl(rinv, (r & 3) + 8 * (r >> 2) + 4 * h);
        int q = (r & 3) + 8 * (r >> 2) + 4 * h;
        osw[((0 * 4 + (q31 >> 3)) * QW + q) * 8 + (l & 7)] = f2bf(o0[r] * rn);
        osw[((1 * 4 + (q31 >> 3)) * QW + q) * 8 + (l & 7)] = f2bf(o1[r] * rn);
        osw[((2 * 4 + (q31 >> 3)) * QW + q) * 8 + (l & 7)] = f2bf(o2[r] * rn);
        osw[((3 * 4 + (q31 >> 3)) * QW + q) * 8 + (l & 7)] = f2bf(o3[r] * rn);
    }

    // ---- final conv out[256][q] = w_attn * O^T, + bias, residual
    const float sg = sigma[0];
    for (int cht = 0; cht < 8; ++cht) {
        f32x16 e = ZERO16;
#pragma unroll
        for (int ks16 = 0; ks16 < 8; ++ks16) {
            short8v wf = *(const short8v*)&wab[(size_t)(cht * 32 + q31) * DV + ks16 * 16 + h * 8];
            short8v of = *(const short8v*)&osw[((ks16 * 2 + h) * QW + q31) * 8];
            e = __builtin_amdgcn_mfma_f32_32x32x16_bf16(wf, of, e, 0, 0, 0);
        }
#pragma unroll
        for (int r = 0; r < 16; ++r) {
            int ch = cht * 32 + (r & 3) + 8 * (r >> 2) + 4 * h;
            size_t idx = ((size_t)b * 256 + ch) * NPIX + p0 + q31;
            out[idx] = fmaf(sg, e[r] + b_attn[ch], x[idx]);
        }
    }
}

extern "C" void kernel_launch(void* const* d_in, const int* in_sizes, int n_in,
                              void* d_out, int out_size, void* d_ws, size_t ws_size,
                              hipStream_t stream) {
    const float* x       = (const float*)d_in[0];
    const float* w_theta = (const float*)d_in[1];
    const float* b_theta = (const float*)d_in[2];
    const float* w_phi   = (const float*)d_in[3];
    const float* b_phi   = (const float*)d_in[4];
    const float* w_g     = (const float*)d_in[5];
    const float* b_g     = (const float*)d_in[6];
    const float* w_attn  = (const float*)d_in[7];
    const float* b_attn  = (const float*)d_in[8];
    const float* sigma   = (const float*)d_in[9];
    float* out = (float*)d_out;

    unsigned short* Qg  = (unsigned short*)d_ws;                 // 16*4096*32
    unsigned short* Kg  = Qg + (size_t)BATCH * NPIX * DQK;       // 16*4*1024*8
    unsigned short* Vg  = Kg + (size_t)BATCH * 4 * NP4 * 8;      // 16*128*128*8
    unsigned short* wab = Vg + (size_t)BATCH * 128 * DV * 8;     // 256*128

    conv_theta_k   <<<dim3(NPIX / 64, BATCH), 256, 0, stream>>>(x, w_theta, b_theta, Qg);
    conv_phi_pool_k<<<dim3(NP4 / 64, BATCH), 256, 0, stream>>>(x, w_phi, b_phi, Kg);
    conv_g_pool_k  <<<dim3(NP4 / 32, BATCH), 256, 0, stream>>>(x, w_g, b_g, Vg);
    wcvt_k         <<<dim3(128), 256, 0, stream>>>(w_attn, wab, 256 * DV);
    flash_k        <<<dim3(NPIX / QT, BATCH), 256, 0, stream>>>(
        Qg, Kg, Vg, wab, b_attn, sigma, x, out);
}

// Round 3
// 104.420 us; speedup vs baseline: 9.4532x; 2.4243x over previous
//
#include <hip/hip_runtime.h>
#include <math.h>

#define BATCH 16
#define CIN   256
#define NPIX  4096   // 64*64
#define NP4   1024   // 32*32 pooled
#define DQK   32     // C/8
#define DV    128    // C/2
#define KT    64     // keys per flash tile
#define QW    32     // queries per wave
#define QT    128    // queries per WG (4 waves)

typedef __attribute__((ext_vector_type(8)))  short short8v;
typedef __attribute__((ext_vector_type(16))) float f32x16;

#define ZERO16 {0.f,0.f,0.f,0.f,0.f,0.f,0.f,0.f,0.f,0.f,0.f,0.f,0.f,0.f,0.f,0.f}

__device__ __forceinline__ unsigned short f2bf(float f) {
    unsigned u = __float_as_uint(f);
    u += 0x7FFFu + ((u >> 16) & 1u);          // round-to-nearest-even
    return (unsigned short)(u >> 16);
}

__device__ __forceinline__ void gload_lds16(const void* g, void* l) {
    __builtin_amdgcn_global_load_lds(
        (const __attribute__((address_space(1))) unsigned int*)g,
        (__attribute__((address_space(3))) unsigned int*)l, 16, 0, 0);
}

// -------- weight conversion: wqkv[192][256] = {theta,phi,g}, wab[256][128] --
__global__ void wcvt_k(const float* __restrict__ wt, const float* __restrict__ wp,
                       const float* __restrict__ wg, const float* __restrict__ wa,
                       unsigned short* __restrict__ wqkv, unsigned short* __restrict__ wab)
{
    int i = blockIdx.x * 256 + threadIdx.x;
    if (i < 192 * 256) {
        int row = i >> 8, c = i & 255;
        float v = row < 32 ? wt[row * 256 + c]
                : row < 64 ? wp[(row - 32) * 256 + c]
                           : wg[(row - 64) * 256 + c];
        wqkv[i] = f2bf(v);
    } else {
        int j = i - 192 * 256;
        if (j < 256 * DV) wab[j] = f2bf(wa[j]);
    }
}

// -------- fused QKV conv (MFMA) + 2x2 maxpool for K,V ----------------------
// WG: 256 thr, tile = 192 out-ch x 128 pixels (2 image rows). Grid (32, B).
__global__ __launch_bounds__(256, 2) void conv_qkv_k(
    const float* __restrict__ x, const unsigned short* __restrict__ wqkv,
    const float* __restrict__ b_theta, const float* __restrict__ b_phi,
    const float* __restrict__ b_g, unsigned short* __restrict__ Qg,
    unsigned short* __restrict__ Kg, unsigned short* __restrict__ Vg)
{
    __shared__ __align__(16) union {
        unsigned short xs[2][2][128][8];   // [buf][k>>3][pixel][k&7]  8 KB
        float pool[2][160][32];            // [row-half][pooled ch][window] 40 KB
    } u;

    const int b    = blockIdx.y;
    const int tile = blockIdx.x;              // two image rows
    const int pixb = tile * 128;
    const int t    = threadIdx.x;
    const int wv   = t >> 6, l = t & 63, h = l >> 5, q31 = l & 31;
    const int sp   = t & 127, skb = t >> 7;   // staging: pixel, k-half

    const float* xb = x + (size_t)b * CIN * NPIX + pixb + sp;

    f32x16 acc[6];
#pragma unroll
    for (int i = 0; i < 6; ++i) acc[i] = ZERO16;

    // prologue: stage k-step 0
    float xr[8];
#pragma unroll
    for (int j = 0; j < 8; ++j) xr[j] = xb[(size_t)(skb * 8 + j) * NPIX];
    {
        unsigned pk[4];
#pragma unroll
        for (int jj = 0; jj < 4; ++jj)
            pk[jj] = f2bf(xr[2*jj]) | ((unsigned)f2bf(xr[2*jj+1]) << 16);
        *(uint4*)&u.xs[0][skb][sp][0] = *(uint4*)pk;
    }
    __syncthreads();

    for (int ks = 0; ks < 16; ++ks) {
        const int cur = ks & 1;
        if (ks < 15) {
            const float* xn = xb + (size_t)((ks + 1) * 16 + skb * 8) * NPIX;
#pragma unroll
            for (int j = 0; j < 8; ++j) xr[j] = xn[(size_t)j * NPIX];
        }
        short8v bf = *(const short8v*)&u.xs[cur][h][wv * 32 + q31][0];
#pragma unroll
        for (int rb = 0; rb < 6; ++rb) {
            short8v af = *(const short8v*)&wqkv[(size_t)(rb * 32 + q31) * 256 + ks * 16 + h * 8];
            acc[rb] = __builtin_amdgcn_mfma_f32_32x32x16_bf16(af, bf, acc[rb], 0, 0, 0);
        }
        if (ks < 15) {
            unsigned pk[4];
#pragma unroll
            for (int jj = 0; jj < 4; ++jj)
                pk[jj] = f2bf(xr[2*jj]) | ((unsigned)f2bf(xr[2*jj+1]) << 16);
            *(uint4*)&u.xs[cur ^ 1][skb][sp][0] = *(uint4*)pk;
        }
        __syncthreads();
    }

    // ---- Q epilogue (rb 0): full-res, bf16 [p][32]
    {
        int pix = pixb + wv * 32 + q31;
        unsigned short* qout = &Qg[((size_t)b * NPIX + pix) * DQK];
#pragma unroll
        for (int m = 0; m < 4; ++m) {
            unsigned pk2[2];
            float v0 = acc[0][m*4+0] + b_theta[4*h + 8*m + 0];
            float v1 = acc[0][m*4+1] + b_theta[4*h + 8*m + 1];
            float v2 = acc[0][m*4+2] + b_theta[4*h + 8*m + 2];
            float v3 = acc[0][m*4+3] + b_theta[4*h + 8*m + 3];
            pk2[0] = f2bf(v0) | ((unsigned)f2bf(v1) << 16);
            pk2[1] = f2bf(v2) | ((unsigned)f2bf(v3) << 16);
            *(uint2*)&qout[8*m + 4*h] = *(uint2*)pk2;
        }
    }

    // ---- pooled epilogue (rb 1..5): horizontal max via shfl, halves to LDS
#pragma unroll
    for (int rb = 1; rb < 6; ++rb) {
#pragma unroll
        for (int r = 0; r < 16; ++r) {
            float v  = acc[rb][r];
            float o  = __shfl_xor(v, 1);
            float mx = fmaxf(v, o);
            if ((q31 & 1) == 0) {
                int row = (r & 3) + 8 * (r >> 2) + 4 * h;
                u.pool[wv >> 1][(rb - 1) * 32 + row][(wv & 1) * 16 + (q31 >> 1)] = mx;
            }
        }
    }
    __syncthreads();

    // ---- vertical max + bias + scatter to K/V frag layouts
    {
        int wx = t & 31;
        int pp = tile * 32 + wx;                      // pooled pixel
#pragma unroll
        for (int i = 0; i < 20; ++i) {
            int ch = (t >> 5) * 20 + i;               // 0..159
            float v = fmaxf(u.pool[0][ch][wx], u.pool[1][ch][wx]);
            if (ch < 32) {
                v += b_phi[ch];
                Kg[(((size_t)b * 4 + (ch >> 3)) * NP4 + pp) * 8 + (ch & 7)] = f2bf(v);
            } else {
                int c = ch - 32;
                v += b_g[c];
                Vg[((size_t)b * 128 + (pp >> 3)) * (DV * 8) + (size_t)c * 8 + (pp & 7)] = f2bf(v);
            }
        }
    }
}

// ------- fused: flash attention (MFMA) + final conv (MFMA) + residual -------
__global__ __launch_bounds__(256, 2) void flash_k(
    const unsigned short* __restrict__ Qg, const unsigned short* __restrict__ Kg,
    const unsigned short* __restrict__ Vg, const unsigned short* __restrict__ wab,
    const float* __restrict__ b_attn, const float* __restrict__ sigma,
    const float* __restrict__ x, float* __restrict__ out)
{
    __shared__ __align__(16) union {
        struct {
            unsigned short ks[4 * KT * 8];   // [d>>3][k 64][d&7]  4KB
            unsigned short vs[8 * DV * 8];   // [k>>3][c 128][k&7] 16KB
        } s;
        unsigned short os[4][16 * QW * 8];   // per-wave [c>>3][q 32][c&7] 32KB
    } u;

    const int b   = blockIdx.y;
    const int t   = threadIdx.x;
    const int wv  = t >> 6;
    const int l   = t & 63;
    const int h   = l >> 5;
    const int q31 = l & 31;
    const int p0  = blockIdx.x * QT + wv * QW;          // wave's pixel base

    short8v qf0 = *(const short8v*)&Qg[((size_t)b * NPIX + p0 + q31) * DQK + h * 8];
    short8v qf1 = *(const short8v*)&Qg[((size_t)b * NPIX + p0 + q31) * DQK + 16 + h * 8];

    f32x16 o0 = ZERO16, o1 = ZERO16, o2 = ZERO16, o3 = ZERO16;
    float m = -3.0e38f, lsum = 0.f;

    const size_t kbase = (size_t)b * 4 * NP4 * 8;
    const size_t vbase = (size_t)b * 128 * DV * 8;

    for (int kt = 0; kt < NP4 / KT; ++kt) {
#pragma unroll
        for (int j = 0; j < 5; ++j) {
            int cid = wv * 5 + j;
            if (cid < 4) {
                gload_lds16(&Kg[kbase + ((size_t)cid * NP4 + kt * KT + l) * 8],
                            &u.s.ks[cid * 512]);
            } else {
                int c2 = cid - 4;
                gload_lds16(&Vg[vbase + (size_t)kt * 8192 + c2 * 512 + l * 8],
                            &u.s.vs[c2 * 512]);
            }
        }
        __syncthreads();

        f32x16 s0 = ZERO16, s1 = ZERO16;
        {
            short8v kf;
            kf = *(const short8v*)&u.s.ks[((0 + h) * KT + 0 + q31) * 8];
            s0 = __builtin_amdgcn_mfma_f32_32x32x16_bf16(kf, qf0, s0, 0, 0, 0);
            kf = *(const short8v*)&u.s.ks[((2 + h) * KT + 0 + q31) * 8];
            s0 = __builtin_amdgcn_mfma_f32_32x32x16_bf16(kf, qf1, s0, 0, 0, 0);
            kf = *(const short8v*)&u.s.ks[((0 + h) * KT + 32 + q31) * 8];
            s1 = __builtin_amdgcn_mfma_f32_32x32x16_bf16(kf, qf0, s1, 0, 0, 0);
            kf = *(const short8v*)&u.s.ks[((2 + h) * KT + 32 + q31) * 8];
            s1 = __builtin_amdgcn_mfma_f32_32x32x16_bf16(kf, qf1, s1, 0, 0, 0);
        }

        float mx = s0[0];
#pragma unroll
        for (int r = 1; r < 16; ++r) mx = fmaxf(mx, s0[r]);
#pragma unroll
        for (int r = 0; r < 16; ++r) mx = fmaxf(mx, s1[r]);
        mx = fmaxf(mx, __shfl_xor(mx, 32));

        bool nskip = !__all(mx <= m + 8.0f);            // defer-max (T13)
        if (nskip) {
            float mnew = fmaxf(m, mx);
            float scale = __expf(m - mnew);
            m = mnew;
            lsum *= scale;
#pragma unroll
            for (int r = 0; r < 16; ++r) {
                float sc = __shfl(scale, (r & 3) + 8 * (r >> 2) + 4 * h);
                o0[r] *= sc; o1[r] *= sc; o2[r] *= sc; o3[r] *= sc;
            }
        }

        float rs = 0.f;
#pragma unroll
        for (int r = 0; r < 16; ++r) { s0[r] = __expf(s0[r] - m); rs += s0[r]; }
#pragma unroll
        for (int r = 0; r < 16; ++r) { s1[r] = __expf(s1[r] - m); rs += s1[r]; }
        rs += __shfl_xor(rs, 32);
        lsum += rs;

        unsigned ca[8], cb[8], da[8], db[8];
#pragma unroll
        for (int j = 0; j < 8; ++j) {
            asm("v_cvt_pk_bf16_f32 %0, %1, %2" : "=v"(ca[j]) : "v"(s0[2*j]), "v"(s0[2*j+1]));
            asm("v_cvt_pk_bf16_f32 %0, %1, %2" : "=v"(cb[j]) : "v"(s1[2*j]), "v"(s1[2*j+1]));
        }
#pragma unroll
        for (int j = 0; j < 8; ++j) {
            da[j] = (unsigned)__shfl_xor((int)ca[j], 32);
            db[j] = (unsigned)__shfl_xor((int)cb[j], 32);
        }
        union { unsigned uu[4]; short8v v; } pa[4];
#pragma unroll
        for (int ksl = 0; ksl < 2; ++ksl) {
            pa[ksl].uu[0]     = h ? da[4*ksl+2] : ca[4*ksl+0];
            pa[ksl].uu[1]     = h ? da[4*ksl+3] : ca[4*ksl+1];
            pa[ksl].uu[2]     = h ? ca[4*ksl+2] : da[4*ksl+0];
            pa[ksl].uu[3]     = h ? ca[4*ksl+3] : da[4*ksl+1];
            pa[2+ksl].uu[0]   = h ? db[4*ksl+2] : cb[4*ksl+0];
            pa[2+ksl].uu[1]   = h ? db[4*ksl+3] : cb[4*ksl+1];
            pa[2+ksl].uu[2]   = h ? cb[4*ksl+2] : db[4*ksl+0];
            pa[2+ksl].uu[3]   = h ? cb[4*ksl+3] : db[4*ksl+1];
        }

#pragma unroll
        for (int ks16 = 0; ks16 < 4; ++ks16) {
            const unsigned short* vrow = &u.s.vs[((ks16 * 2 + h) * DV) * 8];
            o0 = __builtin_amdgcn_mfma_f32_32x32x16_bf16(pa[ks16].v,
                     *(const short8v*)&vrow[(0  + q31) * 8], o0, 0, 0, 0);
            o1 = __builtin_amdgcn_mfma_f32_32x32x16_bf16(pa[ks16].v,
                     *(const short8v*)&vrow[(32 + q31) * 8], o1, 0, 0, 0);
            o2 = __builtin_amdgcn_mfma_f32_32x32x16_bf16(pa[ks16].v,
                     *(const short8v*)&vrow[(64 + q31) * 8], o2, 0, 0, 0);
            o3 = __builtin_amdgcn_mfma_f32_32x32x16_bf16(pa[ks16].v,
                     *(const short8v*)&vrow[(96 + q31) * 8], o3, 0, 0, 0);
        }
        __syncthreads();
    }

    float rinv = 1.0f / lsum;
    unsigned short* osw = u.os[wv];
#pragma unroll
    for (int r = 0; r < 16; ++r) {
        float rn = __shfl(rinv, (r & 3) + 8 * (r >> 2) + 4 * h);
        int q = (r & 3) + 8 * (r >> 2) + 4 * h;
        osw[((0 * 4 + (q31 >> 3)) * QW + q) * 8 + (l & 7)] = f2bf(o0[r] * rn);
        osw[((1 * 4 + (q31 >> 3)) * QW + q) * 8 + (l & 7)] = f2bf(o1[r] * rn);
        osw[((2 * 4 + (q31 >> 3)) * QW + q) * 8 + (l & 7)] = f2bf(o2[r] * rn);
        osw[((3 * 4 + (q31 >> 3)) * QW + q) * 8 + (l & 7)] = f2bf(o3[r] * rn);
    }

    const float sg = sigma[0];
    for (int cht = 0; cht < 8; ++cht) {
        f32x16 e = ZERO16;
#pragma unroll
        for (int ks16 = 0; ks16 < 8; ++ks16) {
            short8v wf = *(const short8v*)&wab[(size_t)(cht * 32 + q31) * DV + ks16 * 16 + h * 8];
            short8v of = *(const short8v*)&osw[((ks16 * 2 + h) * QW + q31) * 8];
            e = __builtin_amdgcn_mfma_f32_32x32x16_bf16(wf, of, e, 0, 0, 0);
        }
#pragma unroll
        for (int r = 0; r < 16; ++r) {
            int ch = cht * 32 + (r & 3) + 8 * (r >> 2) + 4 * h;
            size_t idx = ((size_t)b * 256 + ch) * NPIX + p0 + q31;
            out[idx] = fmaf(sg, e[r] + b_attn[ch], x[idx]);
        }
    }
}

extern "C" void kernel_launch(void* const* d_in, const int* in_sizes, int n_in,
                              void* d_out, int out_size, void* d_ws, size_t ws_size,
                              hipStream_t stream) {
    const float* x       = (const float*)d_in[0];
    const float* w_theta = (const float*)d_in[1];
    const float* b_theta = (const float*)d_in[2];
    const float* w_phi   = (const float*)d_in[3];
    const float* b_phi   = (const float*)d_in[4];
    const float* w_g     = (const float*)d_in[5];
    const float* b_g     = (const float*)d_in[6];
    const float* w_attn  = (const float*)d_in[7];
    const float* b_attn  = (const float*)d_in[8];
    const float* sigma   = (const float*)d_in[9];
    float* out = (float*)d_out;

    unsigned short* Qg   = (unsigned short*)d_ws;                 // 16*4096*32
    unsigned short* Kg   = Qg + (size_t)BATCH * NPIX * DQK;       // 16*4*1024*8
    unsigned short* Vg   = Kg + (size_t)BATCH * 4 * NP4 * 8;      // 16*128*128*8
    unsigned short* wab  = Vg + (size_t)BATCH * 128 * DV * 8;     // 256*128
    unsigned short* wqkv = wab + (size_t)256 * DV;                // 192*256

    wcvt_k    <<<dim3((192 * 256 + 256 * DV + 255) / 256), 256, 0, stream>>>(
        w_theta, w_phi, w_g, w_attn, wqkv, wab);
    conv_qkv_k<<<dim3(NPIX / 128, BATCH), 256, 0, stream>>>(
        x, wqkv, b_theta, b_phi, b_g, Qg, Kg, Vg);
    flash_k   <<<dim3(NPIX / QT, BATCH), 256, 0, stream>>>(
        Qg, Kg, Vg, wab, b_attn, sigma, x, out);
}

// Round 6
// 99.488 us; speedup vs baseline: 9.9219x; 1.0496x over previous
//
#include <hip/hip_runtime.h>
#include <math.h>

#define BATCH 16
#define CIN   256
#define NPIX  4096   // 64*64
#define NP4   1024   // 32*32 pooled
#define DQK   32     // C/8
#define DV    128    // C/2
#define KT    64     // keys per flash tile
#define QW    32     // queries per wave
#define QT    128    // queries per WG (4 waves)

typedef __attribute__((ext_vector_type(8)))  short short8v;
typedef __attribute__((ext_vector_type(16))) float f32x16;

#define ZERO16 {0.f,0.f,0.f,0.f,0.f,0.f,0.f,0.f,0.f,0.f,0.f,0.f,0.f,0.f,0.f,0.f}

__device__ __forceinline__ unsigned short f2bf(float f) {
    unsigned u = __float_as_uint(f);
    u += 0x7FFFu + ((u >> 16) & 1u);          // round-to-nearest-even
    return (unsigned short)(u >> 16);
}

__device__ __forceinline__ unsigned cvtpk(float a, float b) {
    unsigned r;
    asm("v_cvt_pk_bf16_f32 %0, %1, %2" : "=v"(r) : "v"(a), "v"(b));
    return r;
}

__device__ __forceinline__ void gload_lds16(const void* g, void* l) {
    __builtin_amdgcn_global_load_lds(
        (const __attribute__((address_space(1))) unsigned int*)g,
        (__attribute__((address_space(3))) unsigned int*)l, 16, 0, 0);
}

// drain ALL outstanding global_load_lds BEFORE the barrier (cross-wave LDS
// visibility; compiler's implicit drain may land after s_barrier).
#define VMCNT0_BARRIER() do { \
    asm volatile("s_waitcnt vmcnt(0)" ::: "memory"); \
    __syncthreads(); \
} while (0)

// -------- weight conversion: wqkv[192][256] = {theta,phi,g}, wab[256][128] --
__global__ void wcvt_k(const float* __restrict__ wt, const float* __restrict__ wp,
                       const float* __restrict__ wg, const float* __restrict__ wa,
                       unsigned short* __restrict__ wqkv, unsigned short* __restrict__ wab)
{
    int i = blockIdx.x * 256 + threadIdx.x;
    if (i < 192 * 256) {
        int row = i >> 8, c = i & 255;
        float v = row < 32 ? wt[row * 256 + c]
                : row < 64 ? wp[(row - 32) * 256 + c]
                           : wg[(row - 64) * 256 + c];
        wqkv[i] = f2bf(v);
    } else {
        int j = i - 192 * 256;
        if (j < 256 * DV) wab[j] = f2bf(wa[j]);
    }
}

// -------- fused QKV conv (MFMA) + 2x2 maxpool for K,V ----------------------
// WG: 256 thr, tile = 192 out-ch x 128 pixels (2 image rows). Grid (32, B).
__global__ __launch_bounds__(256, 2) void conv_qkv_k(
    const float* __restrict__ x, const unsigned short* __restrict__ wqkv,
    const float* __restrict__ b_theta, const float* __restrict__ b_phi,
    const float* __restrict__ b_g, unsigned short* __restrict__ Qg,
    unsigned short* __restrict__ Kg, unsigned short* __restrict__ Vg)
{
    __shared__ __align__(16) union {
        unsigned short xs[2][2][128][8];   // [buf][k>>3][pixel][k&7]  8 KB
        float pool[2][160][32];            // [row-half][pooled ch][window] 40 KB
    } u;

    const int b    = blockIdx.y;
    const int tile = blockIdx.x;              // two image rows
    const int pixb = tile * 128;
    const int t    = threadIdx.x;
    const int wv   = t >> 6, l = t & 63, h = l >> 5, q31 = l & 31;
    const int sp   = t & 127, skb = t >> 7;   // staging: pixel, k-half

    const float* xb = x + (size_t)b * CIN * NPIX + pixb + sp;

    f32x16 acc[6];
#pragma unroll
    for (int i = 0; i < 6; ++i) acc[i] = ZERO16;

    // prologue: ks=0 -> buf0, prefetch ks=1 into regs (2-deep pipeline)
    float xa[8], xbr[8];
#pragma unroll
    for (int j = 0; j < 8; ++j) xa[j] = xb[(size_t)(skb * 8 + j) * NPIX];
    {
        unsigned pk[4];
#pragma unroll
        for (int jj = 0; jj < 4; ++jj) pk[jj] = cvtpk(xa[2*jj], xa[2*jj+1]);
        *(uint4*)&u.xs[0][skb][sp][0] = *(uint4*)pk;
    }
#pragma unroll
    for (int j = 0; j < 8; ++j) xbr[j] = xb[(size_t)(16 + skb * 8 + j) * NPIX];
    __syncthreads();

    for (int ks = 0; ks < 16; ks += 2) {
        // ---- even sub-step (logical ks, reads buf0)
        if (ks < 14) {
            const float* xn = xb + (size_t)((ks + 2) * 16 + skb * 8) * NPIX;
#pragma unroll
            for (int j = 0; j < 8; ++j) xa[j] = xn[(size_t)j * NPIX];
        }
        {
            short8v bf = *(const short8v*)&u.xs[0][h][wv * 32 + q31][0];
#pragma unroll
            for (int rb = 0; rb < 6; ++rb) {
                short8v af = *(const short8v*)&wqkv[(size_t)(rb * 32 + q31) * 256 + ks * 16 + h * 8];
                acc[rb] = __builtin_amdgcn_mfma_f32_32x32x16_bf16(af, bf, acc[rb], 0, 0, 0);
            }
        }
        {   // write buf1 <- ks+1 data (loaded last sub-step)
            unsigned pk[4];
#pragma unroll
            for (int jj = 0; jj < 4; ++jj) pk[jj] = cvtpk(xbr[2*jj], xbr[2*jj+1]);
            *(uint4*)&u.xs[1][skb][sp][0] = *(uint4*)pk;
        }
        __syncthreads();

        // ---- odd sub-step (logical ks+1, reads buf1)
        if (ks < 14) {  // FIX (was ks<12): ks=12 must load k-block 15 for the ks=14 pair
            const float* xn = xb + (size_t)((ks + 3) * 16 + skb * 8) * NPIX;
#pragma unroll
            for (int j = 0; j < 8; ++j) xbr[j] = xn[(size_t)j * NPIX];
        }
        {
            short8v bf = *(const short8v*)&u.xs[1][h][wv * 32 + q31][0];
#pragma unroll
            for (int rb = 0; rb < 6; ++rb) {
                short8v af = *(const short8v*)&wqkv[(size_t)(rb * 32 + q31) * 256 + (ks + 1) * 16 + h * 8];
                acc[rb] = __builtin_amdgcn_mfma_f32_32x32x16_bf16(af, bf, acc[rb], 0, 0, 0);
            }
        }
        if (ks < 14) {  // write buf0 <- ks+2 data
            unsigned pk[4];
#pragma unroll
            for (int jj = 0; jj < 4; ++jj) pk[jj] = cvtpk(xa[2*jj], xa[2*jj+1]);
            *(uint4*)&u.xs[0][skb][sp][0] = *(uint4*)pk;
        }
        __syncthreads();
    }

    // ---- Q epilogue (rb 0): full-res, bf16 [p][32]
    {
        int pix = pixb + wv * 32 + q31;
        unsigned short* qout = &Qg[((size_t)b * NPIX + pix) * DQK];
#pragma unroll
        for (int m = 0; m < 4; ++m) {
            unsigned pk2[2];
            float v0 = acc[0][m*4+0] + b_theta[4*h + 8*m + 0];
            float v1 = acc[0][m*4+1] + b_theta[4*h + 8*m + 1];
            float v2 = acc[0][m*4+2] + b_theta[4*h + 8*m + 2];
            float v3 = acc[0][m*4+3] + b_theta[4*h + 8*m + 3];
            pk2[0] = cvtpk(v0, v1);
            pk2[1] = cvtpk(v2, v3);
            *(uint2*)&qout[8*m + 4*h] = *(uint2*)pk2;
        }
    }

    // ---- pooled epilogue (rb 1..5): horizontal max via shfl, halves to LDS
#pragma unroll
    for (int rb = 1; rb < 6; ++rb) {
#pragma unroll
        for (int r = 0; r < 16; ++r) {
            float v  = acc[rb][r];
            float o  = __shfl_xor(v, 1);
            float mx = fmaxf(v, o);
            if ((q31 & 1) == 0) {
                int row = (r & 3) + 8 * (r >> 2) + 4 * h;
                u.pool[wv >> 1][(rb - 1) * 32 + row][(wv & 1) * 16 + (q31 >> 1)] = mx;
            }
        }
    }
    __syncthreads();

    // ---- vertical max + bias + scatter to K/V frag layouts
    {
        int wx = t & 31;
        int pp = tile * 32 + wx;                      // pooled pixel
#pragma unroll
        for (int i = 0; i < 20; ++i) {
            int ch = (t >> 5) * 20 + i;               // 0..159
            float v = fmaxf(u.pool[0][ch][wx], u.pool[1][ch][wx]);
            if (ch < 32) {
                v += b_phi[ch];
                Kg[(((size_t)b * 4 + (ch >> 3)) * NP4 + pp) * 8 + (ch & 7)] = f2bf(v);
            } else {
                int c = ch - 32;
                v += b_g[c];
                Vg[((size_t)b * 128 + (pp >> 3)) * (DV * 8) + (size_t)c * 8 + (pp & 7)] = f2bf(v);
            }
        }
    }
}

// ------- fused: flash attention (MFMA) + final conv (MFMA) + residual -------
__global__ __launch_bounds__(256, 2) void flash_k(
    const unsigned short* __restrict__ Qg, const unsigned short* __restrict__ Kg,
    const unsigned short* __restrict__ Vg, const unsigned short* __restrict__ wab,
    const float* __restrict__ b_attn, const float* __restrict__ sigma,
    const float* __restrict__ x, float* __restrict__ out)
{
    __shared__ __align__(16) union {
        struct {
            unsigned short ks[2][4 * KT * 8];   // [buf][d>>3][k 64][d&7]  2x4KB
            unsigned short vs[2][8 * DV * 8];   // [buf][k>>3][c 128][k&7] 2x16KB
        } s;
        unsigned short os[4][16 * QW * 8];      // per-wave [c>>3][q 32][c&7] 32KB
    } u;

    const int b   = blockIdx.y;
    const int t   = threadIdx.x;
    const int wv  = t >> 6;
    const int l   = t & 63;
    const int h   = l >> 5;
    const int q31 = l & 31;
    const int p0  = blockIdx.x * QT + wv * QW;          // wave's pixel base

    const size_t kbase = (size_t)b * 4 * NP4 * 8;
    const size_t vbase = (size_t)b * 128 * DV * 8;

    // stage tile kt into buffer bu (5 chunks/wave, wave-uniform LDS dest)
    auto STAGE = [&](int bu, int kt) {
#pragma unroll
        for (int j = 0; j < 5; ++j) {
            int cid = wv * 5 + j;
            if (cid < 4) {
                gload_lds16(&Kg[kbase + ((size_t)cid * NP4 + kt * KT + l) * 8],
                            &u.s.ks[bu][cid * 512]);
            } else {
                int c2 = cid - 4;
                gload_lds16(&Vg[vbase + (size_t)kt * 8192 + c2 * 512 + l * 8],
                            &u.s.vs[bu][c2 * 512]);
            }
        }
    };

    short8v qf0 = *(const short8v*)&Qg[((size_t)b * NPIX + p0 + q31) * DQK + h * 8];
    short8v qf1 = *(const short8v*)&Qg[((size_t)b * NPIX + p0 + q31) * DQK + 16 + h * 8];

    f32x16 o0 = ZERO16, o1 = ZERO16, o2 = ZERO16, o3 = ZERO16;
    float m = -3.0e38f, lsum = 0.f;

    STAGE(0, 0);
    VMCNT0_BARRIER();                       // buf0 ready for ALL waves
    int cur = 0;

    for (int kt = 0; kt < NP4 / KT; ++kt) {
        if (kt < NP4 / KT - 1) STAGE(cur ^ 1, kt + 1);   // flies under this tile's compute

        f32x16 s0 = ZERO16, s1 = ZERO16;
        {
            short8v kf;
            kf = *(const short8v*)&u.s.ks[cur][((0 + h) * KT + 0 + q31) * 8];
            s0 = __builtin_amdgcn_mfma_f32_32x32x16_bf16(kf, qf0, s0, 0, 0, 0);
            kf = *(const short8v*)&u.s.ks[cur][((2 + h) * KT + 0 + q31) * 8];
            s0 = __builtin_amdgcn_mfma_f32_32x32x16_bf16(kf, qf1, s0, 0, 0, 0);
            kf = *(const short8v*)&u.s.ks[cur][((0 + h) * KT + 32 + q31) * 8];
            s1 = __builtin_amdgcn_mfma_f32_32x32x16_bf16(kf, qf0, s1, 0, 0, 0);
            kf = *(const short8v*)&u.s.ks[cur][((2 + h) * KT + 32 + q31) * 8];
            s1 = __builtin_amdgcn_mfma_f32_32x32x16_bf16(kf, qf1, s1, 0, 0, 0);
        }

        float mx = s0[0];
#pragma unroll
        for (int r = 1; r < 16; ++r) mx = fmaxf(mx, s0[r]);
#pragma unroll
        for (int r = 0; r < 16; ++r) mx = fmaxf(mx, s1[r]);
        mx = fmaxf(mx, __shfl_xor(mx, 32));

        bool nskip = !__all(mx <= m + 8.0f);            // defer-max (T13)
        if (nskip) {
            float mnew = fmaxf(m, mx);
            float scale = __expf(m - mnew);
            m = mnew;
            lsum *= scale;
#pragma unroll
            for (int r = 0; r < 16; ++r) {
                float sc = __shfl(scale, (r & 3) + 8 * (r >> 2) + 4 * h);
                o0[r] *= sc; o1[r] *= sc; o2[r] *= sc; o3[r] *= sc;
            }
        }

        float rs = 0.f;
#pragma unroll
        for (int r = 0; r < 16; ++r) { s0[r] = __expf(s0[r] - m); rs += s0[r]; }
#pragma unroll
        for (int r = 0; r < 16; ++r) { s1[r] = __expf(s1[r] - m); rs += s1[r]; }
        rs += __shfl_xor(rs, 32);
        lsum += rs;

        unsigned ca[8], cb[8], da[8], db[8];
#pragma unroll
        for (int j = 0; j < 8; ++j) {
            ca[j] = cvtpk(s0[2*j], s0[2*j+1]);
            cb[j] = cvtpk(s1[2*j], s1[2*j+1]);
        }
#pragma unroll
        for (int j = 0; j < 8; ++j) {
            da[j] = (unsigned)__shfl_xor((int)ca[j], 32);
            db[j] = (unsigned)__shfl_xor((int)cb[j], 32);
        }
        union { unsigned uu[4]; short8v v; } pa[4];
#pragma unroll
        for (int ksl = 0; ksl < 2; ++ksl) {
            pa[ksl].uu[0]     = h ? da[4*ksl+2] : ca[4*ksl+0];
            pa[ksl].uu[1]     = h ? da[4*ksl+3] : ca[4*ksl+1];
            pa[ksl].uu[2]     = h ? ca[4*ksl+2] : da[4*ksl+0];
            pa[ksl].uu[3]     = h ? ca[4*ksl+3] : da[4*ksl+1];
            pa[2+ksl].uu[0]   = h ? db[4*ksl+2] : cb[4*ksl+0];
            pa[2+ksl].uu[1]   = h ? db[4*ksl+3] : cb[4*ksl+1];
            pa[2+ksl].uu[2]   = h ? cb[4*ksl+2] : db[4*ksl+0];
            pa[2+ksl].uu[3]   = h ? cb[4*ksl+3] : db[4*ksl+1];
        }

#pragma unroll
        for (int ks16 = 0; ks16 < 4; ++ks16) {
            const unsigned short* vrow = &u.s.vs[cur][((ks16 * 2 + h) * DV) * 8];
            o0 = __builtin_amdgcn_mfma_f32_32x32x16_bf16(pa[ks16].v,
                     *(const short8v*)&vrow[(0  + q31) * 8], o0, 0, 0, 0);
            o1 = __builtin_amdgcn_mfma_f32_32x32x16_bf16(pa[ks16].v,
                     *(const short8v*)&vrow[(32 + q31) * 8], o1, 0, 0, 0);
            o2 = __builtin_amdgcn_mfma_f32_32x32x16_bf16(pa[ks16].v,
                     *(const short8v*)&vrow[(64 + q31) * 8], o2, 0, 0, 0);
            o3 = __builtin_amdgcn_mfma_f32_32x32x16_bf16(pa[ks16].v,
                     *(const short8v*)&vrow[(96 + q31) * 8], o3, 0, 0, 0);
        }

        VMCNT0_BARRIER();   // next tile's stage landed (all waves) + buf[cur] readers done
        cur ^= 1;
    }

    // loop barrier above separates last ds_reads from os union reuse
    float rinv = 1.0f / lsum;
    unsigned short* osw = u.os[wv];
#pragma unroll
    for (int r = 0; r < 16; ++r) {
        float rn = __shfl(rinv, (r & 3) + 8 * (r >> 2) + 4 * h);
        int q = (r & 3) + 8 * (r >> 2) + 4 * h;
        osw[((0 * 4 + (q31 >> 3)) * QW + q) * 8 + (l & 7)] = f2bf(o0[r] * rn);
        osw[((1 * 4 + (q31 >> 3)) * QW + q) * 8 + (l & 7)] = f2bf(o1[r] * rn);
        osw[((2 * 4 + (q31 >> 3)) * QW + q) * 8 + (l & 7)] = f2bf(o2[r] * rn);
        osw[((3 * 4 + (q31 >> 3)) * QW + q) * 8 + (l & 7)] = f2bf(o3[r] * rn);
    }

    const float sg = sigma[0];
    for (int cht = 0; cht < 8; ++cht) {
        f32x16 e = ZERO16;
#pragma unroll
        for (int ks16 = 0; ks16 < 8; ++ks16) {
            short8v wf = *(const short8v*)&wab[(size_t)(cht * 32 + q31) * DV + ks16 * 16 + h * 8];
            short8v of = *(const short8v*)&osw[((ks16 * 2 + h) * QW + q31) * 8];
            e = __builtin_amdgcn_mfma_f32_32x32x16_bf16(wf, of, e, 0, 0, 0);
        }
#pragma unroll
        for (int r = 0; r < 16; ++r) {
            int ch = cht * 32 + (r & 3) + 8 * (r >> 2) + 4 * h;
            size_t idx = ((size_t)b * 256 + ch) * NPIX + p0 + q31;
            out[idx] = fmaf(sg, e[r] + b_attn[ch], x[idx]);
        }
    }
}

extern "C" void kernel_launch(void* const* d_in, const int* in_sizes, int n_in,
                              void* d_out, int out_size, void* d_ws, size_t ws_size,
                              hipStream_t stream) {
    const float* x       = (const float*)d_in[0];
    const float* w_theta = (const float*)d_in[1];
    const float* b_theta = (const float*)d_in[2];
    const float* w_phi   = (const float*)d_in[3];
    const float* b_phi   = (const float*)d_in[4];
    const float* w_g     = (const float*)d_in[5];
    const float* b_g     = (const float*)d_in[6];
    const float* w_attn  = (const float*)d_in[7];
    const float* b_attn  = (const float*)d_in[8];
    const float* sigma   = (const float*)d_in[9];
    float* out = (float*)d_out;

    unsigned short* Qg   = (unsigned short*)d_ws;                 // 16*4096*32
    unsigned short* Kg   = Qg + (size_t)BATCH * NPIX * DQK;       // 16*4*1024*8
    unsigned short* Vg   = Kg + (size_t)BATCH * 4 * NP4 * 8;      // 16*128*128*8
    unsigned short* wab  = Vg + (size_t)BATCH * 128 * DV * 8;     // 256*128
    unsigned short* wqkv = wab + (size_t)256 * DV;                // 192*256

    wcvt_k    <<<dim3((192 * 256 + 256 * DV + 255) / 256), 256, 0, stream>>>(
        w_theta, w_phi, w_g, w_attn, wqkv, wab);
    conv_qkv_k<<<dim3(NPIX / 128, BATCH), 256, 0, stream>>>(
        x, wqkv, b_theta, b_phi, b_g, Qg, Kg, Vg);
    flash_k   <<<dim3(NPIX / QT, BATCH), 256, 0, stream>>>(
        Qg, Kg, Vg, wab, b_attn, sigma, x, out);
}